// Round 8
// baseline (269.076 us; speedup 1.0000x reference)
//
#include <hip/hip_runtime.h>
#include <math.h>

#define ROWLEN 16384
#define BLOCK  512
#define NCHUNK 8              // 8 x float4 = 32 floats / thread; 512*32 = 16384
#define NWAVE  (BLOCK / 64)
#define NMOM   9              // central moments p = 2..10
#define EPSV   1e-10
#define NBLOCKS 256           // persistent: 1 block/CU
#define RPB    (8192 / NBLOCKS)   // 32 rows per block

// lgkm-only workgroup barrier: does NOT drain vmcnt, so async prefetch DMA
// stays in flight across the cross-wave reductions. (Correctness-proven in
// round 6 at absmax 0.03125.)
__device__ __forceinline__ void sync_lds()
{
    asm volatile("s_waitcnt lgkmcnt(0)" ::: "memory");
    __builtin_amdgcn_s_barrier();
    asm volatile("" ::: "memory");
}

// Async global->LDS DMA, 16B per lane (1 KB per wave-instruction).
// LDS dest is wave-uniform base + lane*16; global src is per-lane.
__device__ __forceinline__ void gload_lds16(const float* gsrc, float* ldst)
{
    __builtin_amdgcn_global_load_lds(
        (const __attribute__((address_space(1))) void*)gsrc,
        (__attribute__((address_space(3))) void*)ldst, 16, 0, 0);
}

__global__ __launch_bounds__(BLOCK) void moments_kernel(
    const float* __restrict__ y, float* __restrict__ out)
{
    const int tid  = threadIdx.x;
    const int wave = tid >> 6;
    const int lane = tid & 63;
    const int row0 = blockIdx.x * RPB;

    // double-buffered row storage: 2 x 64 KB (+ reduction scratch)
    __shared__ float ldsrow[2][ROWLEN];
    __shared__ double wsum[NWAVE];
    __shared__ double wacc[NWAVE][NMOM];

    float* cur = &ldsrow[0][0];
    float* nxt = &ldsrow[1][0];

    // Each wave DMAs its contiguous 8 KB stripe as 8 x 1 KB instructions.
    // Exactly 8 vmem ops per wave per issue -> counted vmcnt(8) below is exact.
    auto issue = [&](float* dst, int row) {
        const float* src = y + (size_t)row * ROWLEN;
        const int stripe = wave * (ROWLEN / NWAVE);        // in floats
#pragma unroll
        for (int i = 0; i < 8; ++i) {
            const int off = stripe + i * 256;              // 256 floats = 1 KB
            gload_lds16(src + off + lane * 4, dst + off);
        }
    };

    issue(cur, row0);                                      // prologue prefetch

#pragma unroll 1
    for (int r = 0; r < RPB; ++r) {
        const int row = row0 + r;

        // Prefetch next row BEFORE waiting on this one: queue never drains.
        if (r + 1 < RPB) {
            issue(nxt, row + 1);
            asm volatile("s_waitcnt vmcnt(8)" ::: "memory");  // cur complete
        } else {
            asm volatile("s_waitcnt vmcnt(0)" ::: "memory");
        }
        __builtin_amdgcn_s_barrier();                      // cur visible to all

        const float4* vrow = reinterpret_cast<const float4*>(cur);

        // ---- phase 1: mean (numerics identical to round-3 passing kernel) --
        double tsum = 0.0;
#pragma unroll
        for (int i = 0; i < NCHUNK; ++i) {
            const float4 v = vrow[i * BLOCK + tid];
            float s = (v.x + v.y) + (v.z + v.w);
            tsum += (double)s;
        }
#pragma unroll
        for (int off = 32; off > 0; off >>= 1)
            tsum += __shfl_xor(tsum, off, 64);
        if (lane == 0) wsum[wave] = tsum;
        sync_lds();

        double total = 0.0;
#pragma unroll
        for (int w = 0; w < NWAVE; ++w) total += wsum[w];
        const double meand = total * (1.0 / (double)ROWLEN);
        const float  meanf = (float)meand;

        // ---- phase 2: central power sums p=2..10 ----
        double acc[NMOM];
#pragma unroll
        for (int p = 0; p < NMOM; ++p) acc[p] = 0.0;

#pragma unroll
        for (int i = 0; i < NCHUNK; ++i) {
            const float4 v = vrow[i * BLOCK + tid];

            float part[NMOM];
#pragma unroll
            for (int p = 0; p < NMOM; ++p) part[p] = 0.0f;

            const float zs[4] = { v.x - meanf, v.y - meanf,
                                  v.z - meanf, v.w - meanf };
#pragma unroll
            for (int e = 0; e < 4; ++e) {
                const float z = zs[e];
                float zp = z * z;            // p = 2
                part[0] += zp;
#pragma unroll
                for (int p = 1; p < NMOM; ++p) {
                    zp *= z;                 // p = 2 + p
                    part[p] += zp;
                }
            }
#pragma unroll
            for (int p = 0; p < NMOM; ++p) acc[p] += (double)part[p];
        }

#pragma unroll
        for (int p = 0; p < NMOM; ++p) {
#pragma unroll
            for (int off = 32; off > 0; off >>= 1)
                acc[p] += __shfl_xor(acc[p], off, 64);
        }
        if (lane == 0) {
#pragma unroll
            for (int p = 0; p < NMOM; ++p) wacc[wave][p] = acc[p];
        }
        sync_lds();

        // ---- epilogue: thread 0 ----
        if (tid == 0) {
            double sums[NMOM];
#pragma unroll
            for (int p = 0; p < NMOM; ++p) {
                double s = 0.0;
#pragma unroll
                for (int w = 0; w < NWAVE; ++w) s += wacc[w][p];
                sums[p] = s;
            }

            float* o = out + (size_t)row * 10;

            const double stdv = sqrt(sums[0] / (double)(ROWLEN - 1)) + EPSV;

            const double sg0 = (meand > 0.0) ? 1.0 : (meand < 0.0 ? -1.0 : 0.0);
            o[0] = (float)(sg0 * log(fabs(meand) + EPSV));

            double sp = stdv;                      // std^1
            for (int p = 0; p < NMOM; ++p) {
                sp *= stdv;                        // std^(p+2)
                const double cm  = sums[p] * (1.0 / (double)ROWLEN);
                const double nrm = cm / (sp + EPSV);
                const double sg  = (nrm > 0.0) ? 1.0 : (nrm < 0.0 ? -1.0 : 0.0);
                double mj = sg * log(fabs(nrm) + EPSV);
                mj = fmin(10.0, fmax(-10.0, mj));
                o[1 + p] = (float)mj;
            }
        }

        float* t = cur; cur = nxt; nxt = t;        // uniform pointer swap
    }
}

extern "C" void kernel_launch(void* const* d_in, const int* in_sizes, int n_in,
                              void* d_out, int out_size, void* d_ws, size_t ws_size,
                              hipStream_t stream)
{
    const float* y = (const float*)d_in[0];
    float* out = (float*)d_out;
    moments_kernel<<<NBLOCKS, BLOCK, 0, stream>>>(y, out);
}

// Round 9
// 113.207 us; speedup vs baseline: 2.3768x; 2.3768x over previous
//
#include <hip/hip_runtime.h>
#include <math.h>

#define ROWLEN 16384
#define BLOCK  256
#define NCHUNK 16             // 16 x float4 = 64 floats / thread; 256*64 = 16384
#define NWAVE  (BLOCK / 64)
#define NMOM   9              // central moments p = 2..10
#define EPSV   1e-10

typedef float f32x2 __attribute__((ext_vector_type(2)));

// VOP3P packed fp32: 2 elements per instruction (gfx90a+, present on gfx950).
__device__ __forceinline__ f32x2 pk_mul(f32x2 a, f32x2 b)
{
    f32x2 d;
    asm("v_pk_mul_f32 %0, %1, %2" : "=v"(d) : "v"(a), "v"(b));
    return d;
}
__device__ __forceinline__ f32x2 pk_add(f32x2 a, f32x2 b)
{
    f32x2 d;
    asm("v_pk_add_f32 %0, %1, %2" : "=v"(d) : "v"(a), "v"(b));
    return d;
}

// Structure identical to the round-5 PASSING kernel (115.7us): register
// row-cache, 4 blocks/CU phase diversity. Only the phase-2 inner math is
// changed: packed-f32 power chains (halves fp32 VALU) and f64 flush every
// 8 elements instead of 4 (halves f64 cvt+add), shrinking the compute that
// the block-convoy leaves exposed.
__global__ __launch_bounds__(BLOCK, 4) void moments_kernel(
    const float* __restrict__ y, float* __restrict__ out)
{
    const int row  = blockIdx.x;
    const int tid  = threadIdx.x;
    const int wave = tid >> 6;
    const int lane = tid & 63;

    const float4* yrow = reinterpret_cast<const float4*>(y + (size_t)row * ROWLEN);

    // ---- single HBM read: keep the whole row in registers ----
    float4 v[NCHUNK];
#pragma unroll
    for (int i = 0; i < NCHUNK; ++i)
        v[i] = yrow[i * BLOCK + tid];

    // ---- phase 1: mean (identical to round 5) ----
    double tsum = 0.0;
#pragma unroll
    for (int i = 0; i < NCHUNK; ++i) {
        float s = (v[i].x + v[i].y) + (v[i].z + v[i].w);
        tsum += (double)s;
    }
#pragma unroll
    for (int off = 32; off > 0; off >>= 1)
        tsum += __shfl_xor(tsum, off, 64);

    __shared__ double wsum[NWAVE];
    if (lane == 0) wsum[wave] = tsum;
    __syncthreads();

    double total = 0.0;
#pragma unroll
    for (int w = 0; w < NWAVE; ++w) total += wsum[w];

    const double meand = total * (1.0 / (double)ROWLEN);
    const float  meanf = (float)meand;

    // ---- phase 2: central power sums p=2..10, packed-f32 chains ----
    double acc[NMOM];
#pragma unroll
    for (int p = 0; p < NMOM; ++p) acc[p] = 0.0;

#pragma unroll
    for (int i = 0; i < NCHUNK; i += 2) {
        f32x2 part[NMOM];
#pragma unroll
        for (int p = 0; p < NMOM; ++p) part[p] = (f32x2){0.0f, 0.0f};

#pragma unroll
        for (int j = 0; j < 2; ++j) {
            const float4 c = v[i + j];
            const f32x2 za = { c.x - meanf, c.y - meanf };
            const f32x2 zb = { c.z - meanf, c.w - meanf };
            f32x2 pa = pk_mul(za, za);          // z^2
            f32x2 pb = pk_mul(zb, zb);
            part[0] = pk_add(part[0], pa);
            part[0] = pk_add(part[0], pb);
#pragma unroll
            for (int p = 1; p < NMOM; ++p) {
                pa = pk_mul(pa, za);            // z^(p+2)
                pb = pk_mul(pb, zb);
                part[p] = pk_add(part[p], pa);
                part[p] = pk_add(part[p], pb);
            }
        }
        // flush 8-element fp32 partials into f64 accumulators
#pragma unroll
        for (int p = 0; p < NMOM; ++p)
            acc[p] += (double)(part[p].x + part[p].y);
    }

    // ---- wave reduce each accumulator (identical to round 5) ----
#pragma unroll
    for (int p = 0; p < NMOM; ++p) {
#pragma unroll
        for (int off = 32; off > 0; off >>= 1)
            acc[p] += __shfl_xor(acc[p], off, 64);
    }

    __shared__ double wacc[NWAVE][NMOM];
    if (lane == 0) {
#pragma unroll
        for (int p = 0; p < NMOM; ++p) wacc[wave][p] = acc[p];
    }
    __syncthreads();

    // ---- epilogue: thread 0 computes the 10 outputs (identical to round 5) --
    if (tid == 0) {
        double sums[NMOM];
#pragma unroll
        for (int p = 0; p < NMOM; ++p) {
            double s = 0.0;
#pragma unroll
            for (int w = 0; w < NWAVE; ++w) s += wacc[w][p];
            sums[p] = s;
        }

        float* o = out + (size_t)row * 10;

        const double stdv = sqrt(sums[0] / (double)(ROWLEN - 1)) + EPSV;

        const double mean = meand;
        const double sgn0 = (mean > 0.0) ? 1.0 : (mean < 0.0 ? -1.0 : 0.0);
        o[0] = (float)(sgn0 * log(fabs(mean) + EPSV));

        double sp = stdv;                      // std^1
        for (int p = 0; p < NMOM; ++p) {
            sp *= stdv;                        // std^(p+2)
            const double cm  = sums[p] * (1.0 / (double)ROWLEN);
            const double nrm = cm / (sp + EPSV);
            const double sg  = (nrm > 0.0) ? 1.0 : (nrm < 0.0 ? -1.0 : 0.0);
            double mj = sg * log(fabs(nrm) + EPSV);
            mj = fmin(10.0, fmax(-10.0, mj));
            o[1 + p] = (float)mj;
        }
    }
}

extern "C" void kernel_launch(void* const* d_in, const int* in_sizes, int n_in,
                              void* d_out, int out_size, void* d_ws, size_t ws_size,
                              hipStream_t stream)
{
    const float* y = (const float*)d_in[0];
    float* out = (float*)d_out;
    const int B = in_sizes[0] / ROWLEN;   // 8192 rows
    moments_kernel<<<B, BLOCK, 0, stream>>>(y, out);
}

// Round 10
// 102.725 us; speedup vs baseline: 2.6194x; 1.1020x over previous
//
#include <hip/hip_runtime.h>
#include <math.h>

#define ROWLEN 16384
#define BLOCK  256
#define NCHUNK 16             // 16 x float4 = 64 floats / thread; 256*64 = 16384
#define NWAVE  (BLOCK / 64)
#define NMOM   9              // central moments p = 2..10
#define EPSV   1e-10

typedef float f32x2 __attribute__((ext_vector_type(2)));

// VOP3P packed fp32: 2 elements per instruction (gfx90a+, present on gfx950).
__device__ __forceinline__ f32x2 pk_mul(f32x2 a, f32x2 b)
{
    f32x2 d;
    asm("v_pk_mul_f32 %0, %1, %2" : "=v"(d) : "v"(a), "v"(b));
    return d;
}
__device__ __forceinline__ f32x2 pk_add(f32x2 a, f32x2 b)
{
    f32x2 d;
    asm("v_pk_add_f32 %0, %1, %2" : "=v"(d) : "v"(a), "v"(b));
    return d;
}

// R9 structure (113.2us) with ONE change: the epilogue. R9 ran 10 software
// f64 log()s serially on thread 0 (~1.7us/row) AFTER the last barrier --
// that sits on the block's retirement path and throttles CU slot turnover
// (HBM needs a slot freed every ~2.5us/CU). Now lanes 0-9 each produce one
// output in parallel; the final log is f32 (arg stays f64 upstream; log of
// a value with |result|<=10 has ~1e-6 f32 error vs 0.27 margin).
__global__ __launch_bounds__(BLOCK, 4) void moments_kernel(
    const float* __restrict__ y, float* __restrict__ out)
{
    const int row  = blockIdx.x;
    const int tid  = threadIdx.x;
    const int wave = tid >> 6;
    const int lane = tid & 63;

    const float4* yrow = reinterpret_cast<const float4*>(y + (size_t)row * ROWLEN);

    // ---- single HBM read: keep the whole row in registers ----
    float4 v[NCHUNK];
#pragma unroll
    for (int i = 0; i < NCHUNK; ++i)
        v[i] = yrow[i * BLOCK + tid];

    // ---- phase 1: mean (identical to R5/R9) ----
    double tsum = 0.0;
#pragma unroll
    for (int i = 0; i < NCHUNK; ++i) {
        float s = (v[i].x + v[i].y) + (v[i].z + v[i].w);
        tsum += (double)s;
    }
#pragma unroll
    for (int off = 32; off > 0; off >>= 1)
        tsum += __shfl_xor(tsum, off, 64);

    __shared__ double wsum[NWAVE];
    if (lane == 0) wsum[wave] = tsum;
    __syncthreads();

    double total = 0.0;
#pragma unroll
    for (int w = 0; w < NWAVE; ++w) total += wsum[w];

    const double meand = total * (1.0 / (double)ROWLEN);
    const float  meanf = (float)meand;

    // ---- phase 2: central power sums p=2..10, packed-f32 chains (as R9) ----
    double acc[NMOM];
#pragma unroll
    for (int p = 0; p < NMOM; ++p) acc[p] = 0.0;

#pragma unroll
    for (int i = 0; i < NCHUNK; i += 2) {
        f32x2 part[NMOM];
#pragma unroll
        for (int p = 0; p < NMOM; ++p) part[p] = (f32x2){0.0f, 0.0f};

#pragma unroll
        for (int j = 0; j < 2; ++j) {
            const float4 c = v[i + j];
            const f32x2 za = { c.x - meanf, c.y - meanf };
            const f32x2 zb = { c.z - meanf, c.w - meanf };
            f32x2 pa = pk_mul(za, za);          // z^2
            f32x2 pb = pk_mul(zb, zb);
            part[0] = pk_add(part[0], pa);
            part[0] = pk_add(part[0], pb);
#pragma unroll
            for (int p = 1; p < NMOM; ++p) {
                pa = pk_mul(pa, za);            // z^(p+2)
                pb = pk_mul(pb, zb);
                part[p] = pk_add(part[p], pa);
                part[p] = pk_add(part[p], pb);
            }
        }
        // flush 8-element fp32 partials into f64 accumulators
#pragma unroll
        for (int p = 0; p < NMOM; ++p)
            acc[p] += (double)(part[p].x + part[p].y);
    }

    // ---- wave reduce each accumulator (identical to R9) ----
#pragma unroll
    for (int p = 0; p < NMOM; ++p) {
#pragma unroll
        for (int off = 32; off > 0; off >>= 1)
            acc[p] += __shfl_xor(acc[p], off, 64);
    }

    __shared__ double wacc[NWAVE][NMOM];
    if (lane == 0) {
#pragma unroll
        for (int p = 0; p < NMOM; ++p) wacc[wave][p] = acc[p];
    }
    __syncthreads();

    // ---- epilogue: lanes 0..9 in parallel, one output each ----
    if (tid < 10) {
        const double N = (double)ROWLEN;
        float* o = out + (size_t)row * 10;

        // all participating lanes need the variance sum for std
        double s2 = 0.0;
#pragma unroll
        for (int w = 0; w < NWAVE; ++w) s2 += wacc[w][0];
        const double stdv = sqrt(s2 / (N - 1.0)) + EPSV;

        if (tid == 0) {
            // m0: signed log of |mean|, NOT clipped
            const double sg0 = (meand > 0.0) ? 1.0 : (meand < 0.0 ? -1.0 : 0.0);
            o[0] = (float)sg0 * logf((float)(fabs(meand) + EPSV));
        } else {
            const int p = tid - 1;             // moment index 0..8 (orders 2..10)
            double s = 0.0;
#pragma unroll
            for (int w = 0; w < NWAVE; ++w) s += wacc[w][p];

            double sp = stdv;                  // std^1
            for (int k = 0; k <= p; ++k) sp *= stdv;   // std^(p+2)

            const double cm  = s / N;
            const double nrm = cm / (sp + EPSV);
            const double sg  = (nrm > 0.0) ? 1.0 : (nrm < 0.0 ? -1.0 : 0.0);
            float mj = (float)sg * logf((float)(fabs(nrm) + EPSV));
            mj = fminf(10.0f, fmaxf(-10.0f, mj));
            o[tid] = mj;
        }
    }
}

extern "C" void kernel_launch(void* const* d_in, const int* in_sizes, int n_in,
                              void* d_out, int out_size, void* d_ws, size_t ws_size,
                              hipStream_t stream)
{
    const float* y = (const float*)d_in[0];
    float* out = (float*)d_out;
    const int B = in_sizes[0] / ROWLEN;   // 8192 rows
    moments_kernel<<<B, BLOCK, 0, stream>>>(y, out);
}